// Round 8
// baseline (364.032 us; speedup 1.0000x reference)
//
#include <hip/hip_runtime.h>
#include <math.h>

// Plenoxels renderer, round 8 = round 7 + occupancy push.
//  - 32B voxel records: 27 SH fp8(e4m3) + sigma fp16 + pad; vox = 64MiB.
//  - render: 4 samples/lane, 256-sample chunks, 2 chunks/ray, 8192 waves.
//    Per-sample state shrunk to {a, alpha*sigmoid(rgb)} (4 regs) so the
//    kernel fits 128 VGPRs -> __launch_bounds__(256,4) = 16 waves/CU.
//  - whole-wave early exit past the ray's box exit.

typedef float f2v __attribute__((ext_vector_type(2)));

namespace {
constexpr float kRadius   = 1.3f;
constexpr int   kRes      = 128;
constexpr float kStep     = 2.0f * 1.3f / 128.0f / 2.0f;   // 0.01015625
constexpr int   kNI       = 443;                           // N_INTRS - 1
constexpr int   kNRays    = 4096;
constexpr int   kChStride = kRes * kRes * kRes;            // 2097152 voxels
constexpr int   kCh       = 28;
constexpr int   kRecBytes = 32;                            // 27 fp8 + f16 sigma + pad
constexpr size_t kVoxBytes = (size_t)kChStride * kRecBytes; // 64 MiB
constexpr int   kChunks   = 2;                             // 256-sample chunks
constexpr int   kChunks7  = 7;                             // fallback: 64-sample
}

// ---------------------------------------------------------------------------
// Convert grid[c][v] (f32 channel-major) -> vox[v] 32B record.
// bytes 0..26: fp8 e4m3 ch0..26 | byte27: 0 | bytes28..29: f16 sigma | pad.
// ---------------------------------------------------------------------------
__global__ __launch_bounds__(256)
void convert_grid(const float* __restrict__ grid, unsigned char* __restrict__ vox)
{
    const int v = blockIdx.x * 256 + threadIdx.x;          // 8192 blocks
    float c[kCh];
    #pragma unroll
    for (int ch = 0; ch < kCh; ++ch)
        c[ch] = __builtin_nontemporal_load(grid + (size_t)ch * kChStride + v);

    unsigned w[8];
    #pragma unroll
    for (int i = 0; i < 6; ++i) {
        int lo = __builtin_amdgcn_cvt_pk_fp8_f32(c[4*i],   c[4*i+1], 0,  false);
        w[i]   = (unsigned)__builtin_amdgcn_cvt_pk_fp8_f32(c[4*i+2], c[4*i+3], lo, true);
    }
    {   // word 6: ch24,25,26 + pad byte
        int lo = __builtin_amdgcn_cvt_pk_fp8_f32(c[24], c[25], 0,  false);
        w[6]   = (unsigned)__builtin_amdgcn_cvt_pk_fp8_f32(c[26], 0.0f, lo, true);
    }
    {   // word 7: fp16 sigma in low half
        union { unsigned short u; _Float16 h; } cv;
        cv.h = (_Float16)c[27];
        w[7] = (unsigned)cv.u;
    }

    uint4* dst = (uint4*)(vox + (size_t)v * kRecBytes);
    dst[0] = make_uint4(w[0], w[1], w[2], w[3]);
    dst[1] = make_uint4(w[4], w[5], w[6], w[7]);
}

// ---------------------------------------------------------------------------
// Per-sample eval with folded shading.  Returns:
//   a  = 1 - alpha + 1e-10 (or exactly 1.0 for k >= kNI)
//   cR/cG/cB = alpha * sigmoid(rp)  (0 when out of box)
// alpha is reconstructed later as (1+1e-10) - a.
// ---------------------------------------------------------------------------
struct SampleC { float a, cR, cG, cB; };

__device__ __forceinline__ SampleC eval_sample(
    int k, float start, float ox, float oy, float oz,
    float dx, float dy, float dz, float dist,
    const float* __restrict__ shm, const unsigned char* __restrict__ vox)
{
    SampleC s;
    s.a = 1.f; s.cR = s.cG = s.cB = 0.f;
    if (k >= kNI) return s;

    const float t  = start + (float)k * kStep;
    const float px = ox + t*dx;
    const float py = oy + t*dy;
    const float pz = oz + t*dz;
    const bool inb = (px > -kRadius) && (px < kRadius) &&
                     (py > -kRadius) && (py < kRadius) &&
                     (pz > -kRadius) && (pz < kRadius);

    float alpha = 0.0f;
    if (inb) {
        const float cx = fminf(fmaxf((px*(1.0f/kRadius) + 1.0f)*0.5f*127.0f, 0.0f), 127.0f);
        const float cy = fminf(fmaxf((py*(1.0f/kRadius) + 1.0f)*0.5f*127.0f, 0.0f), 127.0f);
        const float cz = fminf(fmaxf((pz*(1.0f/kRadius) + 1.0f)*0.5f*127.0f, 0.0f), 127.0f);
        const float fx0 = floorf(cx), fy0 = floorf(cy), fz0 = floorf(cz);
        const float fx = cx - fx0, fy = cy - fy0, fz = cz - fz0;
        const int ix0 = (int)fx0, iy0 = (int)fy0, iz0 = (int)fz0;
        const int ix1 = min(ix0 + 1, 127);
        const int iy1 = min(iy0 + 1, 127);
        const int iz1 = min(iz0 + 1, 127);

        const float gx0 = 1.0f - fx, gy0 = 1.0f - fy, gz0 = 1.0f - fz;

        const int offs[8] = {
            iz0*(kRes*kRes) + iy0*kRes + ix0,
            iz0*(kRes*kRes) + iy0*kRes + ix1,
            iz0*(kRes*kRes) + iy1*kRes + ix0,
            iz0*(kRes*kRes) + iy1*kRes + ix1,
            iz1*(kRes*kRes) + iy0*kRes + ix0,
            iz1*(kRes*kRes) + iy0*kRes + ix1,
            iz1*(kRes*kRes) + iy1*kRes + ix0,
            iz1*(kRes*kRes) + iy1*kRes + ix1 };
        const float cw[8] = {
            gz0*gy0*gx0, gz0*gy0*fx, gz0*fy*gx0, gz0*fy*fx,
            fz *gy0*gx0, fz *gy0*fx, fz *fy*gx0, fz *fy*fx };

        float rp0 = 0.f, rp1 = 0.f, rp2 = 0.f, sig = 0.f;
        #pragma unroll
        for (int cn = 0; cn < 8; ++cn) {
            const uint4* vp = (const uint4*)(vox + (size_t)offs[cn] * kRecBytes);
            const uint4 u0 = vp[0], u1 = vp[1];

            float f[28];
            const unsigned wd[7] = { u0.x, u0.y, u0.z, u0.w, u1.x, u1.y, u1.z };
            #pragma unroll
            for (int i = 0; i < 7; ++i) {
                const f2v lo = __builtin_amdgcn_cvt_pk_f32_fp8((int)wd[i], false);
                const f2v hi = __builtin_amdgcn_cvt_pk_f32_fp8((int)wd[i], true);
                f[4*i+0] = lo.x; f[4*i+1] = lo.y; f[4*i+2] = hi.x; f[4*i+3] = hi.y;
            }
            union { unsigned short u; _Float16 h; } cv;
            cv.u = (unsigned short)(u1.w & 0xffffu);
            const float sv = (float)cv.h;

            float r = 0.f, g = 0.f, b = 0.f;
            #pragma unroll
            for (int j = 0; j < 9; ++j) {
                r = fmaf(shm[j], f[j],      r);
                g = fmaf(shm[j], f[9 + j],  g);
                b = fmaf(shm[j], f[18 + j], b);
            }
            const float wc = cw[cn];
            rp0 = fmaf(wc, r, rp0);
            rp1 = fmaf(wc, g, rp1);
            rp2 = fmaf(wc, b, rp2);
            sig = fmaf(wc, sv, sig);
        }
        sig = fmaxf(sig, 0.0f);
        alpha = 1.0f - expf(-sig * dist);
        s.cR = alpha * (1.0f / (1.0f + expf(-rp0)));
        s.cG = alpha * (1.0f / (1.0f + expf(-rp1)));
        s.cB = alpha * (1.0f / (1.0f + expf(-rp2)));
    }
    s.a = 1.0f - alpha + 1e-10f;
    return s;
}

__device__ __forceinline__ float wave_scan_prod(float a, int lane, float& total)
{
    float prod = a;
    #pragma unroll
    for (int off = 1; off < 64; off <<= 1) {
        const float y = __shfl_up(prod, off, 64);
        if (lane >= off) prod *= y;
    }
    float excl = __shfl_up(prod, 1, 64);
    if (lane == 0) excl = 1.0f;
    total = __shfl(prod, 63, 64);
    return excl;
}

// ---------------------------------------------------------------------------
// Render one 256-sample chunk of one ray per wave; lane handles samples
// base+lane+{0,64,128,192}.  Emits S_R,S_G,S_B,S_L (unit carry) + P.
// ---------------------------------------------------------------------------
__global__ __launch_bounds__(256, 4)
void render_chunks(const float* __restrict__ rays_o,
                   const float* __restrict__ rays_d,
                   const unsigned char* __restrict__ vox,
                   float* __restrict__ partials)           // (4096,2,5)
{
    const int lane  = threadIdx.x & 63;
    const int W     = blockIdx.x * 4 + (threadIdx.x >> 6); // 8192 waves
    const int ray   = W >> 1;
    const int chunk = W & 1;

    const float ox = rays_o[3*ray+0], oy = rays_o[3*ray+1], oz = rays_o[3*ray+2];
    const float dx = rays_d[3*ray+0], dy = rays_d[3*ray+1], dz = rays_d[3*ray+2];

    const float ppx = ( kRadius - ox)/dx, pnx = (-kRadius - ox)/dx;
    const float ppy = ( kRadius - oy)/dy, pny = (-kRadius - oy)/dy;
    const float ppz = ( kRadius - oz)/dz, pnz = (-kRadius - oz)/dz;
    const float start  = fmaxf(fminf(ppx, pnx), fmaxf(fminf(ppy, pny), fminf(ppz, pnz)));
    const float t_exit = fminf(fmaxf(ppx, pnx), fminf(fmaxf(ppy, pny), fmaxf(ppz, pnz)));

    const int base = chunk * 256;

    // whole-wave early exit: chunk starts beyond box exit (one-step margin)
    if (start + (float)base * kStep > t_exit + kStep) {
        if (lane == 0) {
            float* p = partials + (size_t)(ray * kChunks + chunk) * 5;
            p[0] = 0.f; p[1] = 0.f; p[2] = 0.f; p[3] = 0.f; p[4] = 1.f;
        }
        return;
    }

    const float dnorm = sqrtf(dx*dx + dy*dy + dz*dz);
    const float dist  = kStep * dnorm;

    float shm[9];
    shm[0] =  0.28209479177387814f;
    shm[1] = -0.4886025119029199f * dy;
    shm[2] =  0.4886025119029199f * dz;
    shm[3] = -0.4886025119029199f * dx;
    shm[4] =  1.0925484305920792f * dx * dy;
    shm[5] = -1.0925484305920792f * dy * dz;
    shm[6] =  0.31539156525252005f * (2.0f*dz*dz - dx*dx - dy*dy);
    shm[7] = -1.0925484305920792f * dx * dz;
    shm[8] =  0.5462742152960396f * (dx*dx - dy*dy);

    const SampleC A = eval_sample(base       + lane, start, ox, oy, oz, dx, dy, dz, dist, shm, vox);
    const SampleC B = eval_sample(base +  64 + lane, start, ox, oy, oz, dx, dy, dz, dist, shm, vox);
    const SampleC C = eval_sample(base + 128 + lane, start, ox, oy, oz, dx, dy, dz, dist, shm, vox);
    const SampleC D = eval_sample(base + 192 + lane, start, ox, oy, oz, dx, dy, dz, dist, shm, vox);

    float P0, P1, P2, P3;
    const float eA = wave_scan_prod(A.a, lane, P0);
    const float eB = wave_scan_prod(B.a, lane, P1);
    const float eC = wave_scan_prod(C.a, lane, P2);
    const float eD = wave_scan_prod(D.a, lane, P3);

    // prefixes (unit incoming transmittance)
    const float pA = eA;
    const float pB = P0 * eB;
    const float pC = P0 * P1 * eC;
    const float pD = P0 * P1 * P2 * eD;

    // reconstruct alpha = (1+1e-10) - a  (exact 1e-10 for tail lanes -> ~0)
    const float one = 1.0f + 1e-10f;
    const float sL = pA * (one - A.a) + pB * (one - B.a)
                   + pC * (one - C.a) + pD * (one - D.a);

    float sR = pA * A.cR;  sR = fmaf(pB, B.cR, sR);
    sR = fmaf(pC, C.cR, sR);  sR = fmaf(pD, D.cR, sR);
    float sG = pA * A.cG;  sG = fmaf(pB, B.cG, sG);
    sG = fmaf(pC, C.cG, sG);  sG = fmaf(pD, D.cG, sG);
    float sB = pA * A.cB;  sB = fmaf(pB, B.cB, sB);
    sB = fmaf(pC, C.cB, sB);  sB = fmaf(pD, D.cB, sB);

    const float P = P0 * P1 * P2 * P3;

    float rL = sL;
    float rR = sR, rG = sG, rB = sB;
    #pragma unroll
    for (int off = 32; off > 0; off >>= 1) {
        rR += __shfl_down(rR, off, 64);
        rG += __shfl_down(rG, off, 64);
        rB += __shfl_down(rB, off, 64);
        rL += __shfl_down(rL, off, 64);
    }

    if (lane == 0) {
        float* p = partials + (size_t)(ray * kChunks + chunk) * 5;
        p[0] = rR; p[1] = rG; p[2] = rB; p[3] = rL; p[4] = P;
    }
}

// ---------------------------------------------------------------------------
// Stitch chunk partials: acc += carry * S_c ; carry *= P_c.
// ---------------------------------------------------------------------------
__global__ __launch_bounds__(256)
void combine_chunks(const float* __restrict__ partials, float* __restrict__ out)
{
    const int r = blockIdx.x * 256 + threadIdx.x;          // 16 blocks
    const float* p = partials + (size_t)r * (kChunks * 5);

    float carry = 1.0f, aR = 0.f, aG = 0.f, aB = 0.f, aL = 0.f;
    #pragma unroll
    for (int c = 0; c < kChunks; ++c) {
        aR = fmaf(carry, p[c*5 + 0], aR);
        aG = fmaf(carry, p[c*5 + 1], aG);
        aB = fmaf(carry, p[c*5 + 2], aB);
        aL = fmaf(carry, p[c*5 + 3], aL);
        carry *= p[c*5 + 4];
    }
    const float bg = 1.0f - aL;
    out[3*r + 0] = aR + bg;
    out[3*r + 1] = aG + bg;
    out[3*r + 2] = aB + bg;
}

// ---------------------------------------------------------------------------
// Fallback: direct channel-major render (round-1 style) if ws too small.
// ---------------------------------------------------------------------------
#define TRI8(p) (w000*(p)[o000] + w001*(p)[o001] + w010*(p)[o010] + w011*(p)[o011] \
               + w100*(p)[o100] + w101*(p)[o101] + w110*(p)[o110] + w111*(p)[o111])

__global__ __launch_bounds__(256)
void plenoxel_render_direct(const float* __restrict__ rays_o,
                            const float* __restrict__ rays_d,
                            const float* __restrict__ grid,
                            float* __restrict__ out)
{
    const int lane = threadIdx.x & 63;
    const int ray  = blockIdx.x * 4 + (threadIdx.x >> 6);

    const float ox = rays_o[3*ray+0], oy = rays_o[3*ray+1], oz = rays_o[3*ray+2];
    const float dx = rays_d[3*ray+0], dy = rays_d[3*ray+1], dz = rays_d[3*ray+2];

    const float sx = fminf(( kRadius - ox)/dx, (-kRadius - ox)/dx);
    const float sy = fminf(( kRadius - oy)/dy, (-kRadius - oy)/dy);
    const float sz = fminf(( kRadius - oz)/dz, (-kRadius - oz)/dz);
    const float start = fmaxf(sx, fmaxf(sy, sz));
    const float dnorm = sqrtf(dx*dx + dy*dy + dz*dz);

    float shm[9];
    shm[0] =  0.28209479177387814f;
    shm[1] = -0.4886025119029199f * dy;
    shm[2] =  0.4886025119029199f * dz;
    shm[3] = -0.4886025119029199f * dx;
    shm[4] =  1.0925484305920792f * dx * dy;
    shm[5] = -1.0925484305920792f * dy * dz;
    shm[6] =  0.31539156525252005f * (2.0f*dz*dz - dx*dx - dy*dy);
    shm[7] = -1.0925484305920792f * dx * dz;
    shm[8] =  0.5462742152960396f * (dx*dx - dy*dy);

    float carry = 1.0f;
    float accR = 0.f, accG = 0.f, accB = 0.f, accL = 0.f;

    for (int chunk = 0; chunk < kChunks7; ++chunk) {
        const int k = chunk * 64 + lane;
        float alpha = 0.0f, a = 1.0f;
        float rp0 = 0.f, rp1 = 0.f, rp2 = 0.f;
        bool inb = false;

        if (k < kNI) {
            const float t = start + (float)k * kStep;
            const float dist = kStep * dnorm;
            const float px = ox + t*dx, py = oy + t*dy, pz = oz + t*dz;
            inb = (px > -kRadius) && (px < kRadius) &&
                  (py > -kRadius) && (py < kRadius) &&
                  (pz > -kRadius) && (pz < kRadius);
            float sigma = 0.0f;
            if (inb) {
                const float cx = fminf(fmaxf((px*(1.0f/kRadius) + 1.0f)*0.5f*127.0f, 0.0f), 127.0f);
                const float cy = fminf(fmaxf((py*(1.0f/kRadius) + 1.0f)*0.5f*127.0f, 0.0f), 127.0f);
                const float cz = fminf(fmaxf((pz*(1.0f/kRadius) + 1.0f)*0.5f*127.0f, 0.0f), 127.0f);
                const float fx0 = floorf(cx), fy0 = floorf(cy), fz0 = floorf(cz);
                const float fx = cx - fx0, fy = cy - fy0, fz = cz - fz0;
                const int ix0 = (int)fx0, iy0 = (int)fy0, iz0 = (int)fz0;
                const int ix1 = min(ix0 + 1, 127);
                const int iy1 = min(iy0 + 1, 127);
                const int iz1 = min(iz0 + 1, 127);
                const float gx0 = 1.0f - fx, gy0 = 1.0f - fy, gz0 = 1.0f - fz;
                const float w000 = gz0*gy0*gx0, w001 = gz0*gy0*fx;
                const float w010 = gz0*fy *gx0, w011 = gz0*fy *fx;
                const float w100 = fz *gy0*gx0, w101 = fz *gy0*fx;
                const float w110 = fz *fy *gx0, w111 = fz *fy *fx;
                const int o000 = iz0*(kRes*kRes) + iy0*kRes + ix0;
                const int o001 = iz0*(kRes*kRes) + iy0*kRes + ix1;
                const int o010 = iz0*(kRes*kRes) + iy1*kRes + ix0;
                const int o011 = iz0*(kRes*kRes) + iy1*kRes + ix1;
                const int o100 = iz1*(kRes*kRes) + iy0*kRes + ix0;
                const int o101 = iz1*(kRes*kRes) + iy0*kRes + ix1;
                const int o110 = iz1*(kRes*kRes) + iy1*kRes + ix0;
                const int o111 = iz1*(kRes*kRes) + iy1*kRes + ix1;
                #pragma unroll
                for (int kk = 0; kk < 9; ++kk) {
                    rp0 = fmaf(shm[kk], TRI8(grid + (kk     ) * kChStride), rp0);
                    rp1 = fmaf(shm[kk], TRI8(grid + (kk +  9) * kChStride), rp1);
                    rp2 = fmaf(shm[kk], TRI8(grid + (kk + 18) * kChStride), rp2);
                }
                sigma = fmaxf(TRI8(grid + 27 * kChStride), 0.0f);
            }
            alpha = 1.0f - expf(-sigma * dist);
            a     = 1.0f - alpha + 1e-10f;
        }

        float prod = a;
        #pragma unroll
        for (int off = 1; off < 64; off <<= 1) {
            const float y = __shfl_up(prod, off, 64);
            if (lane >= off) prod *= y;
        }
        float excl = __shfl_up(prod, 1, 64);
        if (lane == 0) excl = 1.0f;
        const float trans = carry * excl;
        const float w = alpha * trans;
        if (inb) {
            accR = fmaf(w, 1.0f / (1.0f + expf(-rp0)), accR);
            accG = fmaf(w, 1.0f / (1.0f + expf(-rp1)), accG);
            accB = fmaf(w, 1.0f / (1.0f + expf(-rp2)), accB);
        }
        accL += w;
        carry *= __shfl(prod, 63, 64);
    }

    #pragma unroll
    for (int off = 32; off > 0; off >>= 1) {
        accR += __shfl_down(accR, off, 64);
        accG += __shfl_down(accG, off, 64);
        accB += __shfl_down(accB, off, 64);
        accL += __shfl_down(accL, off, 64);
    }

    if (lane == 0) {
        const float bg = 1.0f - accL;
        out[3*ray + 0] = accR + bg;
        out[3*ray + 1] = accG + bg;
        out[3*ray + 2] = accB + bg;
    }
}

extern "C" void kernel_launch(void* const* d_in, const int* in_sizes, int n_in,
                              void* d_out, int out_size, void* d_ws, size_t ws_size,
                              hipStream_t stream) {
    const float* rays_o = (const float*)d_in[0];
    const float* rays_d = (const float*)d_in[1];
    const float* data   = (const float*)d_in[2];   // (1,28,128,128,128)
    float* out = (float*)d_out;

    const size_t partBytes = (size_t)kNRays * kChunks * 5 * sizeof(float);
    const size_t need = kVoxBytes + partBytes;     // ~64.2 MB

    if (ws_size >= need) {
        unsigned char* vox = (unsigned char*)d_ws;
        float* partials = (float*)((char*)d_ws + kVoxBytes);

        hipLaunchKernelGGL(convert_grid,
                           dim3(kChStride / 256), dim3(256), 0, stream,
                           data, vox);
        hipLaunchKernelGGL(render_chunks,
                           dim3(kNRays * kChunks / 4), dim3(256), 0, stream,
                           rays_o, rays_d, vox, partials);
        hipLaunchKernelGGL(combine_chunks,
                           dim3(kNRays / 256), dim3(256), 0, stream,
                           partials, out);
    } else {
        hipLaunchKernelGGL(plenoxel_render_direct,
                           dim3(kNRays / 4), dim3(256), 0, stream,
                           rays_o, rays_d, data, out);
    }
}